// Round 3
// baseline (162.821 us; speedup 1.0000x reference)
//
#include <hip/hip_runtime.h>

// ElectronGNN on MI355X (gfx950).  Inputs float32, output float32.
// One block per batch element (512 blocks, 256 threads = 4 waves).
// All contractions mapped to v_mfma_f32_16x16x32_f16 (fp16 operands, fp32 acc):
//   z_s[i,d] = sum_{j,f} ee[i,j,f] * (x[j,d]*we_same[f,d])   (K=256, same-spin j)
//   z_a[i,d] = likewise with we_anti over opposite-spin j     (K=256)
//   z_n[i,d] = sum_{n,f} ne[i,n,f] * (y[n,d]*we_ne[f,d])     (K=128, B precomputed)
//   upd      = x@W0 + z_s@W1 + z_a@W2 + z_n@W3 + b ; x += tanh(upd)
// B-operands staged in LDS as [d][k] (stride 40, 16B aligned) -> ds_read_b128 frags.
// A-frags: ds_read_b128 from row-major fp16 (stride 136) or recomputed from fp16
// distance tables (8 exps per frag).  x residual kept fp32 in C-layout registers.

typedef unsigned short u16;
typedef __attribute__((ext_vector_type(8))) short short8;
typedef __attribute__((ext_vector_type(4))) float f32x4;

__device__ __forceinline__ u16 f2h(float f){
  return __builtin_bit_cast(u16, (_Float16)f);
}
__device__ __forceinline__ float h2f(u16 a){
  return (float)__builtin_bit_cast(_Float16, a);
}

// 8 Gaussian RBF features of distance dd, fp16-packed.
__device__ __forceinline__ short8 rbf8(float dd){
  short8 a;
#pragma unroll
  for (int f = 0; f < 8; f++){
    float u = dd - (4.0f/7.0f)*(float)f;
    a[f] = (short)f2h(__expf(-u*u));
  }
  return a;
}

// ---------------- prep kernel: weight-side B operands into d_ws ----------------
// wupT[l][d][kk] = w_up[l][kk][d]              (3*128*512 fp16)
// ywT [l][d][n*8+f] = y[n][d]*we_ne[l][f][d]   (3*128*128 fp16), y = embed[atypes]
__global__ void gnn_prep(const float* __restrict__ w_up, const float* __restrict__ we_ne,
                         const float* __restrict__ embed, const int* __restrict__ atypes,
                         u16* __restrict__ wupT, u16* __restrict__ ywT){
  int id = blockIdx.x * 256 + threadIdx.x;
  if (id < 3*512*128){
    int kk = id & 511, d = (id >> 9) & 127, l = id >> 16;
    wupT[(l*128 + d)*512 + kk] = f2h(w_up[(l*512 + kk)*128 + d]);
  } else {
    id -= 3*512*128;
    int k = id & 127, d = (id >> 7) & 127, l = id >> 14;
    int n = k >> 3, f = k & 7;
    float y  = embed[atypes[n]*128 + d];
    float wn = we_ne[(l*8 + f)*128 + d];
    ywT[(l*128 + d)*128 + k] = f2h(y * wn);
  }
}

// ---------------- main kernel ----------------
__global__ __launch_bounds__(256, 2) void gnn_main(
    const float* __restrict__ r_g, const float* __restrict__ R_g,
    const float* __restrict__ weS_g, const float* __restrict__ weA_g,
    const float* __restrict__ bup_g,
    const u16* __restrict__ wupT, const u16* __restrict__ ywT,
    float* __restrict__ out)
{
  __shared__ __attribute__((aligned(16))) u16 xb[64][136];      // x, fp16, row-major (17408B)
  __shared__ _Float16 dee[64][64];                              // e-e distances
  __shared__ _Float16 dne[64][16];                              // e-n distances
  __shared__ float bup[128];
  __shared__ __attribute__((aligned(16))) u16 arena[13824];     // 27648 B, multi-use

  const int tid  = threadIdx.x;
  const int b    = blockIdx.x;
  const int lane = tid & 63;
  const int w    = tid >> 6;          // wave id 0..3
  const int col  = lane & 15;         // MFMA m/n index
  const int q    = lane >> 4;         // MFMA quad
  const int i0   = w * 16;            // this wave's row tile
  const int s    = w >> 1;            // spin block of rows (0: i<32, 1: i>=32)
  const int mrow = i0 + col;          // A-frag row

  u16* const zst  = arena;            // [64][136]   (z staging, A-layout)
  u16* const wbuf = arena + 8704;     // [128][40]   (weight-chunk B staging)
  u16* const buf0 = arena;            // [128][40]   (xw chunk for up-row waves)
  u16* const buf1 = arena + 5120;     // [128][40]   (xw chunk for down-row waves)
  u16* const mybuf = (s == 0) ? buf0 : buf1;
  const int bd = tid & 127;           // builder: d row
  const int bg = tid >> 7;            // builder: which buf group
  u16* const bbuf = (bg == 0) ? buf0 : buf1;

  // ---------------- Phase A: distances + x init ----------------
  {
    float* rs = (float*)arena;        // [64][4]
    float* Rs = rs + 64*4;            // [16][4]
    if (tid < 64){
#pragma unroll
      for (int k = 0; k < 3; k++) rs[tid*4+k] = r_g[(b*64+tid)*3 + k];
    } else if (tid < 80){
      int n = tid - 64;
#pragma unroll
      for (int k = 0; k < 3; k++) Rs[n*4+k] = R_g[(b*16+n)*3 + k];
    }
    __syncthreads();
    {
      int i = tid >> 2;
      float x0 = rs[i*4], x1 = rs[i*4+1], x2 = rs[i*4+2];
      int jb = (tid & 3) * 16;
#pragma unroll
      for (int jj = 0; jj < 16; jj++){
        int j = jb + jj;
        float dx = x0 - rs[j*4], dy = x1 - rs[j*4+1], dz = x2 - rs[j*4+2];
        dee[i][j] = (_Float16)sqrtf(dx*dx + dy*dy + dz*dz + 1e-12f);
      }
      int nb = (tid & 3) * 4;
#pragma unroll
      for (int nn = 0; nn < 4; nn++){
        int n = nb + nn;
        float dx = x0 - Rs[n*4], dy = x1 - Rs[n*4+1], dz = x2 - Rs[n*4+2];
        dne[i][n] = (_Float16)sqrtf(dx*dx + dy*dy + dz*dz + 1e-12f);
      }
    }
    __syncthreads();
    {
      int i = tid >> 2;
      int nb = (tid & 3) * 4;
#pragma unroll
      for (int nn = 0; nn < 4; nn++){
        int n = nb + nn;
        short8 p = rbf8((float)dne[i][n]);
        *(short8*)&xb[i][n*8] = p;
      }
    }
    __syncthreads();
  }

  // x residual in fp32, C-layout: rows i0+q*4+rr, col nt*16+col
  f32x4 xr[8];
#pragma unroll
  for (int nt = 0; nt < 8; nt++)
#pragma unroll
    for (int rr = 0; rr < 4; rr++)
      xr[nt][rr] = h2f(xb[i0 + q*4 + rr][nt*16 + col]);

  const f32x4 vzero = {0.f, 0.f, 0.f, 0.f};

  for (int l = 0; l < 3; l++){
    const u16* wT_l  = wupT + (l*128)*512;
    const u16* ywT_l = ywT  + (l*128)*128;

    if (tid < 128) bup[tid] = bup_g[l*128 + tid];
    float wefS[8], wefA[8];
#pragma unroll
    for (int f = 0; f < 8; f++){
      wefS[f] = weS_g[(l*8+f)*128 + bd];
      wefA[f] = weA_g[(l*8+f)*128 + bd];
    }
    __syncthreads();

    f32x4 upd[8], zacc[8];
#pragma unroll
    for (int nt = 0; nt < 8; nt++) upd[nt] = vzero;

    // ---------- x @ W0 ----------
    for (int c = 0; c < 4; c++){
      { int d = tid >> 1, h = (tid & 1) << 4;
        const u16* src = wT_l + d*512 + 32*c + h;
        *(short8*)&wbuf[d*40 + h]     = *(const short8*)src;
        *(short8*)&wbuf[d*40 + h + 8] = *(const short8*)(src + 8); }
      __syncthreads();
      short8 a = *(const short8*)&xb[mrow][32*c + (q<<3)];
#pragma unroll
      for (int nt = 0; nt < 8; nt++){
        short8 bb = *(const short8*)&wbuf[(nt*16+col)*40 + (q<<3)];
        upd[nt] = __builtin_amdgcn_mfma_f32_16x16x32_f16(a, bb, upd[nt], 0, 0, 0);
      }
      __syncthreads();
    }

    // ---------- z_same then z_anti ----------
#pragma unroll 1
    for (int pass = 0; pass < 2; pass++){
      const bool same = (pass == 0);
#pragma unroll
      for (int nt = 0; nt < 8; nt++) zacc[nt] = vzero;
      for (int c = 0; c < 8; c++){
        { // build xw chunk: bbuf[d][jj*8+f] = x[jb+jj][d]*we[f][d]
          int jb = (same ? 32*bg : 32*(1-bg)) + 4*c;
#pragma unroll
          for (int jj = 0; jj < 4; jj++){
            float xv = h2f(xb[jb+jj][bd]);
            short8 p;
#pragma unroll
            for (int f = 0; f < 8; f++)
              p[f] = (short)f2h(xv * (same ? wefS[f] : wefA[f]));
            *(short8*)&bbuf[bd*40 + (jj<<3)] = p;
          }
        }
        __syncthreads();
        int j = (same ? 32*s : 32*(1-s)) + 4*c + q;
        short8 a = rbf8((float)dee[mrow][j]);
        if (same && j == mrow) a = (short8)0;   // no self-interaction
#pragma unroll
        for (int nt = 0; nt < 8; nt++){
          short8 bb = *(const short8*)&mybuf[(nt*16+col)*40 + (q<<3)];
          zacc[nt] = __builtin_amdgcn_mfma_f32_16x16x32_f16(a, bb, zacc[nt], 0, 0, 0);
        }
        __syncthreads();
      }
      // stage z -> zst (fp16, A-layout), then z @ W_{1 or 2}
#pragma unroll
      for (int nt = 0; nt < 8; nt++)
#pragma unroll
        for (int rr = 0; rr < 4; rr++)
          zst[(i0 + q*4 + rr)*136 + nt*16 + col] = f2h(zacc[nt][rr]);
      __syncthreads();
      int kb0 = same ? 128 : 256;
      for (int c = 0; c < 4; c++){
        { int d = tid >> 1, h = (tid & 1) << 4;
          const u16* src = wT_l + d*512 + kb0 + 32*c + h;
          *(short8*)&wbuf[d*40 + h]     = *(const short8*)src;
          *(short8*)&wbuf[d*40 + h + 8] = *(const short8*)(src + 8); }
        __syncthreads();
        short8 a = *(const short8*)&zst[mrow*136 + 32*c + (q<<3)];
#pragma unroll
        for (int nt = 0; nt < 8; nt++){
          short8 bb = *(const short8*)&wbuf[(nt*16+col)*40 + (q<<3)];
          upd[nt] = __builtin_amdgcn_mfma_f32_16x16x32_f16(a, bb, upd[nt], 0, 0, 0);
        }
        __syncthreads();
      }
    }

    // ---------- z_ne ----------
#pragma unroll
    for (int nt = 0; nt < 8; nt++) zacc[nt] = vzero;
    for (int c = 0; c < 4; c++){
      { int d = tid >> 1, h = (tid & 1) << 4;
        const u16* src = ywT_l + d*128 + 32*c + h;
        *(short8*)&wbuf[d*40 + h]     = *(const short8*)src;
        *(short8*)&wbuf[d*40 + h + 8] = *(const short8*)(src + 8); }
      __syncthreads();
      int n = c*4 + q;
      short8 a = rbf8((float)dne[mrow][n]);
#pragma unroll
      for (int nt = 0; nt < 8; nt++){
        short8 bb = *(const short8*)&wbuf[(nt*16+col)*40 + (q<<3)];
        zacc[nt] = __builtin_amdgcn_mfma_f32_16x16x32_f16(a, bb, zacc[nt], 0, 0, 0);
      }
      __syncthreads();
    }
#pragma unroll
    for (int nt = 0; nt < 8; nt++)
#pragma unroll
      for (int rr = 0; rr < 4; rr++)
        zst[(i0 + q*4 + rr)*136 + nt*16 + col] = f2h(zacc[nt][rr]);
    __syncthreads();
    for (int c = 0; c < 4; c++){
      { int d = tid >> 1, h = (tid & 1) << 4;
        const u16* src = wT_l + d*512 + 384 + 32*c + h;
        *(short8*)&wbuf[d*40 + h]     = *(const short8*)src;
        *(short8*)&wbuf[d*40 + h + 8] = *(const short8*)(src + 8); }
      __syncthreads();
      short8 a = *(const short8*)&zst[mrow*136 + 32*c + (q<<3)];
#pragma unroll
      for (int nt = 0; nt < 8; nt++){
        short8 bb = *(const short8*)&wbuf[(nt*16+col)*40 + (q<<3)];
        upd[nt] = __builtin_amdgcn_mfma_f32_16x16x32_f16(a, bb, upd[nt], 0, 0, 0);
      }
      __syncthreads();
    }

    // ---------- epilogue: x += tanh(upd + b) ----------
#pragma unroll
    for (int nt = 0; nt < 8; nt++){
      float bb = bup[nt*16 + col];
#pragma unroll
      for (int rr = 0; rr < 4; rr++){
        float v = upd[nt][rr] + bb;
        float e = __expf(2.0f * v);
        float th = 1.0f - 2.0f * __builtin_amdgcn_rcpf(e + 1.0f);
        xr[nt][rr] += th;
      }
    }
    if (l < 2){
#pragma unroll
      for (int nt = 0; nt < 8; nt++)
#pragma unroll
        for (int rr = 0; rr < 4; rr++)
          xb[i0 + q*4 + rr][nt*16 + col] = f2h(xr[nt][rr]);
      __syncthreads();
    } else {
#pragma unroll
      for (int nt = 0; nt < 8; nt++)
#pragma unroll
        for (int rr = 0; rr < 4; rr++)
          out[(b*64 + i0 + q*4 + rr)*128 + nt*16 + col] = xr[nt][rr];
    }
  }
}

extern "C" void kernel_launch(void* const* d_in, const int* in_sizes, int n_in,
                              void* d_out, int out_size, void* d_ws, size_t ws_size,
                              hipStream_t stream){
  const float* r     = (const float*)d_in[0];
  const float* R     = (const float*)d_in[1];
  const float* embed = (const float*)d_in[2];
  const float* weS   = (const float*)d_in[3];
  const float* weA   = (const float*)d_in[4];
  const float* weN   = (const float*)d_in[5];
  const float* wup   = (const float*)d_in[6];
  const float* bup   = (const float*)d_in[7];
  const int* atyp    = (const int*)d_in[8];

  u16* wupT = (u16*)d_ws;                 // 3*128*512 fp16 = 393216 B
  u16* ywT  = wupT + 3*128*512;           // 3*128*128 fp16 =  98304 B

  gnn_prep<<<960, 256, 0, stream>>>(wup, weN, embed, atyp, wupT, ywT);
  gnn_main<<<512, 256, 0, stream>>>(r, R, weS, weA, bup, wupT, ywT, (float*)d_out);
}